// Round 11
// baseline (29.070 us; speedup 1.0000x reference)
//
#include <hip/hip_runtime.h>

#define B    64
#define T    2000
#define DQ   1024
#define DM   512
#define D    128
#define F    32
#define KK   31
#define WIN  7
#define NCH  32
#define CH   63            // ceil(T/NCH)
#define NCS  (B * NCH)     // 2048 colsum blocks
#define NPQ  (B * 4)       // 256 pq k-slice blocks

// ws layout (floats):
//   part  : [B][NCH][DM]      @ 0                  (1048576 floats)
//   pq4   : [B][4][D]         @ NCS*DM             (32768 floats)
//   vpart : [B][8][WIN][64]x2 @ NCS*DM + NPQ*D     (458752 floats)
#define PQ4_OFF (NCS * DM)
#define VP_OFF  (NCS * DM + NPQ * D)

// out layout (floats):
//   attention  [B][D]  @ 0
//   alignments [B][T]  @ 8192
//   next_state [B][T]  @ 8192 + B*T
//   max_att    [B]     @ 8192 + 2*B*T  (as float)
#define OUT_ALIGN 8192
#define OUT_NEXT  (8192 + B*T)
#define OUT_ARG   (8192 + 2*B*T)

// ---------------- K1: colsum + val + pq (all parallel, no sync) ----------------
//  blocks [0,NCS)            : degenerate colsum partial (b=blk>>5, c=blk&31)
//                              float4 loads, 4 row-groups, LDS reduce
//  blocks [NCS,NCS+B)        : val block for batch b: wave w computes
//                              vpart[b][w][i][lane] = sum_{m in w-slice} mrow[i][m]*Wm2[m][lane]
//  blocks [NCS+B,NCS+B+NPQ)  : pq slice (b, j): pq4[b][j][:] over k in [j*256,(j+1)*256)
__global__ void __launch_bounds__(512)
K1(const float* __restrict__ q, const float* __restrict__ mem,
   const int* __restrict__ pm, const int* __restrict__ ml,
   const float* __restrict__ Wq, const float* __restrict__ Wm,
   float* __restrict__ part, float* __restrict__ pq4, float* __restrict__ vpart) {
    __shared__ float red[4][D];
    __shared__ __align__(16) float mrow[WIN][DM];   // colsum blocks alias 8 KB as red4
    int blk = blockIdx.x;
    int tid = threadIdx.x;

    if (blk < NCS) {
        // ---- degenerate colsum partial: float4, 4 row-groups ----
        int b = blk >> 5, c = blk & 31;
        if (pm[b] < ml[b]) return;              // non-degenerate: nothing to do
        int t0 = c * CH, t1 = t0 + CH;
        if (t1 > T) t1 = T;
        int g = tid >> 7;                        // row group 0..3
        int c4 = tid & 127;                      // float4 column
        const float4* mp4 = (const float4*)(mem + (size_t)b * T * DM) + c4;
        float4 acc = make_float4(0.f, 0.f, 0.f, 0.f);
        #pragma unroll 4
        for (int t = t0 + g; t < t1; t += 4) {
            float4 v = mp4[(size_t)t * (DM / 4)];
            acc.x += v.x; acc.y += v.y; acc.z += v.z; acc.w += v.w;
        }
        float4* red4 = (float4*)mrow;            // 8 KB of the 14 KB scratch
        red4[tid] = acc;
        __syncthreads();
        if (tid < 128) {
            float4 s0 = red4[tid], s1 = red4[tid + 128];
            float4 s2 = red4[tid + 256], s3 = red4[tid + 384];
            const float invT = 1.f / (float)T;
            float4 s;
            s.x = ((s0.x + s1.x) + (s2.x + s3.x)) * invT;
            s.y = ((s0.y + s1.y) + (s2.y + s3.y)) * invT;
            s.z = ((s0.z + s1.z) + (s2.z + s3.z)) * invT;
            s.w = ((s0.w + s1.w) + (s2.w + s3.w)) * invT;
            *((float4*)(part + ((size_t)b * NCH + c) * DM) + tid) = s;
        }
        return;
    }

    if (blk < NCS + B) {
        // ---- val block: m-split energies partials for batch b ----
        int b = blk - NCS;
        int p = pm[b], L = ml[b];
        int wstart = p, wlen = 0;
        if (p < L) { int we = p + WIN; if (we > L) we = L; wlen = we - p; }
        if (wlen == 0) return;
        for (int e = tid; e < WIN * DM; e += 512) {
            int i = e >> 9, m = e & 511;
            mrow[i][m] = (i < wlen) ? mem[((size_t)b * T + wstart + i) * DM + m] : 0.f;
        }
        __syncthreads();
        int lane = tid & 63, wave = tid >> 6;
        const float2* Wm2 = (const float2*)Wm;
        float2 acc[WIN];
        #pragma unroll
        for (int i = 0; i < WIN; ++i) { acc[i].x = 0.f; acc[i].y = 0.f; }
        int m0 = wave * 64;
        for (int mm = 0; mm < 64; ++mm) {
            int m = m0 + mm;
            float2 wrow = Wm2[(size_t)m * 64 + lane];
            #pragma unroll
            for (int i = 0; i < WIN; ++i) {
                float a = mrow[i][m];
                acc[i].x += a * wrow.x;
                acc[i].y += a * wrow.y;
            }
        }
        float2* vp = (float2*)vpart + ((size_t)b * 8 + wave) * (WIN * 64);
        #pragma unroll
        for (int i = 0; i < WIN; ++i) vp[i * 64 + lane] = acc[i];
        return;
    }

    // ---- pq slice ----
    int s = blk - NCS - B;
    int b = s >> 2, j = s & 3;
    int d = tid & 127, kk = tid >> 7;           // kk in [0,4)
    int k0 = j * 256 + kk * 64;
    const float* qp = q + (size_t)b * DQ + k0;
    const float* wp = Wq + (size_t)k0 * D + d;
    float acc = 0.f;
    #pragma unroll 4
    for (int k = 0; k < 64; ++k)
        acc += qp[k] * wp[(size_t)k * D];
    red[kk][d] = acc;
    __syncthreads();
    if (tid < D)
        pq4[((size_t)b * 4 + j) * D + tid] =
            (red[0][tid] + red[1][tid]) + (red[2][tid] + red[3][tid]);
}

// ---------------- K2: per-batch finish (64 light blocks) ----------------
__global__ void __launch_bounds__(512)
K2(const float* __restrict__ pa, const int* __restrict__ pm, const int* __restrict__ ml,
   const float* __restrict__ Wm, const float* __restrict__ ck, const float* __restrict__ cb,
   const float* __restrict__ Wloc, const float* __restrict__ sv, const float* __restrict__ sb,
   const float* __restrict__ part, const float* __restrict__ pq4,
   const float* __restrict__ vpart, float* __restrict__ out) {
    __shared__ float fsh[WIN][F];
    __shared__ float vsh[WIN][D];
    __shared__ float pqs[D];
    __shared__ float esh[WIN];
    __shared__ float ash[WIN];
    __shared__ int   sbest;
    __shared__ __align__(16) float cg[DM + 4 * D];   // deg: ctxs[512] + gpart[512]

    int b = blockIdx.x;
    int tid = threadIdx.x;
    int lane = tid & 63;
    int wave = tid >> 6;
    int p = pm[b], L = ml[b];
    int wstart = p, wlen = 0;
    if (p < L) { int we = p + WIN; if (we > L) we = L; wlen = we - p; }

    if (wlen > 0) {
        // conv location features
        if (tid < WIN * F) {
            int i = tid >> 5, f = tid & 31;
            if (i < wlen) {
                int t = wstart + i;
                float acc = cb[f];
                for (int k = 0; k < KK; ++k) {
                    int tt = t + k - 15;
                    float x = (tt >= 0 && tt < T) ? pa[(size_t)b * T + tt] : 0.f;
                    acc += x * ck[k * F + f];
                }
                fsh[i][f] = acc;
            } else if (i < WIN) {
                fsh[i][f] = 0.f;
            }
        }
        if (tid < D) {
            const float* pp = pq4 + (size_t)b * 4 * D;
            pqs[tid] = (pp[tid] + pp[D + tid]) + (pp[2 * D + tid] + pp[3 * D + tid]) + sb[tid];
        }
        __syncthreads();

        // finish energies: wave i sums the 8 w-partials (fixed order) then tanh
        if (wave < wlen) {
            int i = wave;
            const float2* vp = (const float2*)vpart + (size_t)b * 8 * (WIN * 64);
            float2 s2 = {0.f, 0.f};
            #pragma unroll
            for (int w = 0; w < 8; ++w) {
                float2 v = vp[(size_t)w * (WIN * 64) + i * 64 + lane];
                s2.x += v.x;
                s2.y += v.y;
            }
            ((float2*)vsh[i])[lane] = s2;           // save raw val[i][:]
            const float2* Wl2 = (const float2*)Wloc;
            float p0 = 0.f, p1 = 0.f;
            #pragma unroll
            for (int f = 0; f < F; ++f) {
                float fv = fsh[i][f];
                float2 wv = Wl2[f * 64 + lane];
                p0 += fv * wv.x; p1 += fv * wv.y;
            }
            int c0 = 2 * lane, c1 = c0 + 1;
            float x = sv[c0] * tanhf(s2.x + pqs[c0] + p0)
                    + sv[c1] * tanhf(s2.y + pqs[c1] + p1);
            for (int o = 32; o > 0; o >>= 1) x += __shfl_xor(x, o);
            if (lane == 0) esh[i] = x;
        }
        __syncthreads();

        if (tid == 0) {
            float a[WIN];
            int best = 0;
            float mx = esh[0];
            for (int i = 1; i < wlen; ++i) if (esh[i] > mx) mx = esh[i];
            float s = 0.f;
            for (int i = 0; i < wlen; ++i) { a[i] = expf(esh[i] - mx); s += a[i]; }
            float inv = 1.f / s;
            float ab = -1.f;
            for (int i = 0; i < wlen; ++i) {
                a[i] *= inv;
                if (a[i] > ab) { ab = a[i]; best = i; }
            }
            for (int i = 0; i < WIN; ++i) ash[i] = (i < wlen) ? a[i] : 0.f;
            sbest = wstart + best;
        }
        __syncthreads();

        // attention = sum_i a_i * val[i][:]
        if (tid < D) {
            float a = 0.f;
            for (int i = 0; i < wlen; ++i) a += ash[i] * vsh[i][tid];
            out[b * D + tid] = a;
        }
    } else {
        // ---------------- degenerate: reduce part (fixed order) + GEMV ----------
        float* ctxs = cg;
        float* gpart = cg + DM;
        float s = 0.f;
        #pragma unroll 8
        for (int cc = 0; cc < NCH; ++cc)
            s += part[((size_t)b * NCH + cc) * DM + tid];
        ctxs[tid] = s;
        __syncthreads();
        {
            int col = tid & 127, j = tid >> 7;
            const float* wp = Wm + (size_t)(j * 128) * D + col;
            float acc = 0.f;
            for (int mm = 0; mm < 128; ++mm)
                acc += ctxs[j * 128 + mm] * wp[(size_t)mm * D];
            gpart[j * D + col] = acc;
        }
        __syncthreads();
        if (tid < D)
            out[b * D + tid] = gpart[tid] + gpart[D + tid] + gpart[2 * D + tid] + gpart[3 * D + tid];
    }

    // ---------------- [B,T] outputs + argmax ----------------
    {
        float invT = 1.f / (float)T;
        for (int t = tid; t < T; t += 512) {
            float a;
            if (wlen == 0) a = invT;
            else a = (t >= wstart && t < wstart + wlen) ? ash[t - wstart] : 0.f;
            out[OUT_ALIGN + b * T + t] = a;
            out[OUT_NEXT + b * T + t] = pa[(size_t)b * T + t] + a;
        }
        if (tid == 0) out[OUT_ARG + b] = (float)((wlen > 0) ? sbest : 0);
    }
}

// ---------------- K2L: lowmem all-in-one fallback ----------
__global__ void __launch_bounds__(512)
K2L(const float* __restrict__ q, const float* __restrict__ mem,
    const float* __restrict__ pa, const int* __restrict__ pm, const int* __restrict__ ml,
    const float* __restrict__ Wq, const float* __restrict__ Wm,
    const float* __restrict__ ck, const float* __restrict__ cb,
    const float* __restrict__ Wloc, const float* __restrict__ sv,
    const float* __restrict__ sb, float* __restrict__ out) {
    __shared__ __align__(16) float mrow[WIN][DM];
    __shared__ float fsh[WIN][F];
    __shared__ float2 pacc2[WIN][8][64];
    __shared__ float vsh[WIN][D];
    __shared__ float pqs[D];
    __shared__ float esh[WIN];
    __shared__ float ash[WIN];
    __shared__ int   sbest;

    int b = blockIdx.x;
    int tid = threadIdx.x;
    int lane = tid & 63;
    int wave = tid >> 6;
    int p = pm[b], L = ml[b];
    int wstart = p, wlen = 0;
    if (p < L) { int we = p + WIN; if (we > L) we = L; wlen = we - p; }

    if (wlen > 0) {
        for (int e = tid; e < WIN * DM; e += 512) {
            int i = e >> 9, m = e & 511;
            mrow[i][m] = (i < wlen) ? mem[((size_t)b * T + wstart + i) * DM + m] : 0.f;
        }
        if (tid < WIN * F) {
            int i = tid >> 5, f = tid & 31;
            if (i < wlen) {
                int t = wstart + i;
                float acc = cb[f];
                for (int k = 0; k < KK; ++k) {
                    int tt = t + k - 15;
                    float x = (tt >= 0 && tt < T) ? pa[(size_t)b * T + tt] : 0.f;
                    acc += x * ck[k * F + f];
                }
                fsh[i][f] = acc;
            } else if (i < WIN) {
                fsh[i][f] = 0.f;
            }
        }
        {
            int d = tid & 127, j = tid >> 7;
            int k0 = j * 256;
            const float* qp = q + (size_t)b * DQ + k0;
            float acc = 0.f;
            for (int k = 0; k < 256; ++k)
                acc += qp[k] * Wq[(size_t)(k0 + k) * D + d];
            ((float*)pacc2)[j * D + d] = acc;
            __syncthreads();
            if (tid < D) {
                const float* pp = (const float*)pacc2;
                pqs[tid] = (pp[tid] + pp[D + tid]) + (pp[2 * D + tid] + pp[3 * D + tid]) + sb[tid];
            }
        }
        __syncthreads();
        {
            const float2* Wm2 = (const float2*)Wm;
            float2 acc[WIN];
            #pragma unroll
            for (int i = 0; i < WIN; ++i) { acc[i].x = 0.f; acc[i].y = 0.f; }
            int m0 = wave * 64;
            for (int mm = 0; mm < 64; ++mm) {
                int m = m0 + mm;
                float2 wrow = Wm2[(size_t)m * 64 + lane];
                #pragma unroll
                for (int i = 0; i < WIN; ++i) {
                    float a = mrow[i][m];
                    acc[i].x += a * wrow.x;
                    acc[i].y += a * wrow.y;
                }
            }
            #pragma unroll
            for (int i = 0; i < WIN; ++i) pacc2[i][wave][lane] = acc[i];
        }
        __syncthreads();
        if (wave < wlen) {
            int i = wave;
            float2 s2 = {0.f, 0.f};
            #pragma unroll
            for (int w = 0; w < 8; ++w) {
                s2.x += pacc2[i][w][lane].x;
                s2.y += pacc2[i][w][lane].y;
            }
            ((float2*)vsh[i])[lane] = s2;
            const float2* Wl2 = (const float2*)Wloc;
            float p0 = 0.f, p1 = 0.f;
            #pragma unroll
            for (int f = 0; f < F; ++f) {
                float fv = fsh[i][f];
                float2 wv = Wl2[f * 64 + lane];
                p0 += fv * wv.x; p1 += fv * wv.y;
            }
            int c0 = 2 * lane, c1 = c0 + 1;
            float x = sv[c0] * tanhf(s2.x + pqs[c0] + p0)
                    + sv[c1] * tanhf(s2.y + pqs[c1] + p1);
            for (int o = 32; o > 0; o >>= 1) x += __shfl_xor(x, o);
            if (lane == 0) esh[i] = x;
        }
        __syncthreads();
        if (tid == 0) {
            float a[WIN];
            int best = 0;
            float mx = esh[0];
            for (int i = 1; i < wlen; ++i) if (esh[i] > mx) mx = esh[i];
            float s = 0.f;
            for (int i = 0; i < wlen; ++i) { a[i] = expf(esh[i] - mx); s += a[i]; }
            float inv = 1.f / s;
            float ab = -1.f;
            for (int i = 0; i < wlen; ++i) {
                a[i] *= inv;
                if (a[i] > ab) { ab = a[i]; best = i; }
            }
            for (int i = 0; i < WIN; ++i) ash[i] = (i < wlen) ? a[i] : 0.f;
            sbest = wstart + best;
        }
        __syncthreads();
        if (tid < D) {
            float a = 0.f;
            for (int i = 0; i < wlen; ++i) a += ash[i] * vsh[i][tid];
            out[b * D + tid] = a;
        }
    } else {
        float* ctxs = (float*)mrow;
        float* gpart = ((float*)mrow) + DM;
        const float* mp = mem + (size_t)b * T * DM + tid;
        float a0 = 0.f, a1 = 0.f, a2 = 0.f, a3 = 0.f;
        int t = 0;
        for (; t + 4 <= T; t += 4) {
            a0 += mp[0]; a1 += mp[DM]; a2 += mp[2 * DM]; a3 += mp[3 * DM];
            mp += 4 * (size_t)DM;
        }
        for (; t < T; ++t) { a0 += *mp; mp += DM; }
        ctxs[tid] = ((a0 + a1) + (a2 + a3)) * (1.f / (float)T);
        __syncthreads();
        {
            int col = tid & 127, j = tid >> 7;
            const float* wp = Wm + (size_t)(j * 128) * D + col;
            float acc = 0.f;
            for (int mm = 0; mm < 128; ++mm)
                acc += ctxs[j * 128 + mm] * wp[(size_t)mm * D];
            gpart[j * D + col] = acc;
        }
        __syncthreads();
        if (tid < D)
            out[b * D + tid] = gpart[tid] + gpart[D + tid] + gpart[2 * D + tid] + gpart[3 * D + tid];
    }

    {
        float invT = 1.f / (float)T;
        for (int t = tid; t < T; t += 512) {
            float a;
            if (wlen == 0) a = invT;
            else a = (t >= wstart && t < wstart + wlen) ? ash[t - wstart] : 0.f;
            out[OUT_ALIGN + b * T + t] = a;
            out[OUT_NEXT + b * T + t] = pa[(size_t)b * T + t] + a;
        }
        if (tid == 0) out[OUT_ARG + b] = (float)((wlen > 0) ? sbest : 0);
    }
}

extern "C" void kernel_launch(void* const* d_in, const int* in_sizes, int n_in,
                              void* d_out, int out_size, void* d_ws, size_t ws_size,
                              hipStream_t stream) {
    const float* query = (const float*)d_in[0];
    const float* memory = (const float*)d_in[1];
    const float* prev_align = (const float*)d_in[2];
    const int* prev_max = (const int*)d_in[3];
    const int* mem_len = (const int*)d_in[4];
    const float* Wq = (const float*)d_in[5];
    const float* Wm = (const float*)d_in[6];
    const float* ck = (const float*)d_in[7];
    const float* cb = (const float*)d_in[8];
    const float* Wloc = (const float*)d_in[9];
    const float* sv = (const float*)d_in[10];
    const float* sb = (const float*)d_in[11];
    float* out = (float*)d_out;

    float* part = (float*)d_ws;
    float* pq4 = (float*)d_ws + PQ4_OFF;
    float* vpart = (float*)d_ws + VP_OFF;

    size_t need = (size_t)(VP_OFF + B * 8 * WIN * 64 * 2) * 4;
    int lowmem = (ws_size < need) ? 1 : 0;

    if (!lowmem) {
        K1<<<NCS + B + NPQ, 512, 0, stream>>>(query, memory, prev_max, mem_len,
                                              Wq, Wm, part, pq4, vpart);
        K2<<<B, 512, 0, stream>>>(prev_align, prev_max, mem_len, Wm, ck, cb,
                                  Wloc, sv, sb, part, pq4, vpart, out);
    } else {
        K2L<<<B, 512, 0, stream>>>(query, memory, prev_align, prev_max, mem_len,
                                   Wq, Wm, ck, cb, Wloc, sv, sb, out);
    }
}

// Round 12
// 27.409 us; speedup vs baseline: 1.0606x; 1.0606x over previous
//
#include <hip/hip_runtime.h>

#define B    64
#define T    2000
#define DQ   1024
#define DM   512
#define D    128
#define F    32
#define KK   31
#define WIN  7
#define NCH  32
#define CH   63            // ceil(T/NCH)
#define NCS  (B * NCH)     // 2048 colsum blocks
#define NPQ  (B * 4)       // 256 pq k-slice blocks

// ws layout (floats):
//   part  : [B][NCH][DM]      @ 0                  (1048576 floats)
//   pq4   : [B][4][D]         @ NCS*DM             (32768 floats)
//   vpart : [B][8][WIN][64]x2 @ NCS*DM + NPQ*D     (458752 floats)
#define PQ4_OFF (NCS * DM)
#define VP_OFF  (NCS * DM + NPQ * D)

// out layout (floats):
//   attention  [B][D]  @ 0
//   alignments [B][T]  @ 8192
//   next_state [B][T]  @ 8192 + B*T
//   max_att    [B]     @ 8192 + 2*B*T  (as float)
#define OUT_ALIGN 8192
#define OUT_NEXT  (8192 + B*T)
#define OUT_ARG   (8192 + 2*B*T)

// ---------------- K1: colsum + val + pq (all parallel, no sync) ----------------
//  blocks [0,NCS)            : degenerate colsum partial (b=blk>>5, c=blk&31)
//  blocks [NCS,NCS+B)        : val block for batch b: wave w computes
//                              vpart[b][w][i][lane] = sum_{m in w-slice} mrow[i][m]*Wm2[m][lane]
//  blocks [NCS+B,NCS+B+NPQ)  : pq slice (b, j): pq4[b][j][:] over k in [j*256,(j+1)*256)
__global__ void __launch_bounds__(512)
K1(const float* __restrict__ q, const float* __restrict__ mem,
   const int* __restrict__ pm, const int* __restrict__ ml,
   const float* __restrict__ Wq, const float* __restrict__ Wm,
   float* __restrict__ part, float* __restrict__ pq4, float* __restrict__ vpart) {
    __shared__ float red[4][D];
    __shared__ __align__(16) float mrow[WIN][DM];
    int blk = blockIdx.x;
    int tid = threadIdx.x;

    if (blk < NCS) {
        // ---- degenerate colsum partial (scalar per-wave streams: best measured) ----
        int b = blk >> 5, c = blk & 31;
        if (pm[b] < ml[b]) return;              // non-degenerate: nothing to do
        int t0 = c * CH, t1 = t0 + CH;
        if (t1 > T) t1 = T;
        const float* mp = mem + ((size_t)b * T + t0) * DM + tid;
        float a0 = 0.f, a1 = 0.f, a2 = 0.f, a3 = 0.f;
        int t = t0;
        for (; t + 4 <= t1; t += 4) {
            a0 += mp[0];
            a1 += mp[DM];
            a2 += mp[2 * DM];
            a3 += mp[3 * DM];
            mp += 4 * (size_t)DM;
        }
        for (; t < t1; ++t) { a0 += *mp; mp += DM; }
        part[((size_t)b * NCH + c) * DM + tid] = ((a0 + a1) + (a2 + a3)) * (1.f / (float)T);
        return;
    }

    if (blk < NCS + B) {
        // ---- val block: m-split energies partials for batch b ----
        int b = blk - NCS;
        int p = pm[b], L = ml[b];
        int wstart = p, wlen = 0;
        if (p < L) { int we = p + WIN; if (we > L) we = L; wlen = we - p; }
        if (wlen == 0) return;
        for (int e = tid; e < WIN * DM; e += 512) {
            int i = e >> 9, m = e & 511;
            mrow[i][m] = (i < wlen) ? mem[((size_t)b * T + wstart + i) * DM + m] : 0.f;
        }
        __syncthreads();
        int lane = tid & 63, wave = tid >> 6;
        const float2* Wm2 = (const float2*)Wm;
        float2 acc[WIN];
        #pragma unroll
        for (int i = 0; i < WIN; ++i) { acc[i].x = 0.f; acc[i].y = 0.f; }
        int m0 = wave * 64;
        for (int mm = 0; mm < 64; ++mm) {
            int m = m0 + mm;
            float2 wrow = Wm2[(size_t)m * 64 + lane];
            #pragma unroll
            for (int i = 0; i < WIN; ++i) {
                float a = mrow[i][m];
                acc[i].x += a * wrow.x;
                acc[i].y += a * wrow.y;
            }
        }
        float2* vp = (float2*)vpart + ((size_t)b * 8 + wave) * (WIN * 64);
        #pragma unroll
        for (int i = 0; i < WIN; ++i) vp[i * 64 + lane] = acc[i];
        return;
    }

    // ---- pq slice ----
    int s = blk - NCS - B;
    int b = s >> 2, j = s & 3;
    int d = tid & 127, kk = tid >> 7;           // kk in [0,4)
    int k0 = j * 256 + kk * 64;
    const float* qp = q + (size_t)b * DQ + k0;
    const float* wp = Wq + (size_t)k0 * D + d;
    float acc = 0.f;
    #pragma unroll 4
    for (int k = 0; k < 64; ++k)
        acc += qp[k] * wp[(size_t)k * D];
    red[kk][d] = acc;
    __syncthreads();
    if (tid < D)
        pq4[((size_t)b * 4 + j) * D + tid] =
            (red[0][tid] + red[1][tid]) + (red[2][tid] + red[3][tid]);
}

// ---------------- K2: per-batch finish (64 light blocks) ----------------
__global__ void __launch_bounds__(512)
K2(const float* __restrict__ pa, const int* __restrict__ pm, const int* __restrict__ ml,
   const float* __restrict__ Wm, const float* __restrict__ ck, const float* __restrict__ cb,
   const float* __restrict__ Wloc, const float* __restrict__ sv, const float* __restrict__ sb,
   const float* __restrict__ part, const float* __restrict__ pq4,
   const float* __restrict__ vpart, float* __restrict__ out) {
    __shared__ float fsh[WIN][F];
    __shared__ float vsh[WIN][D];
    __shared__ float pqs[D];
    __shared__ float esh[WIN];
    __shared__ float ash[WIN];
    __shared__ int   sbest;
    __shared__ __align__(16) float cg[DM + 4 * D];   // deg: ctxs[512] + gpart[512]

    int b = blockIdx.x;
    int tid = threadIdx.x;
    int lane = tid & 63;
    int wave = tid >> 6;
    int p = pm[b], L = ml[b];
    int wstart = p, wlen = 0;
    if (p < L) { int we = p + WIN; if (we > L) we = L; wlen = we - p; }

    if (wlen > 0) {
        // conv location features
        if (tid < WIN * F) {
            int i = tid >> 5, f = tid & 31;
            if (i < wlen) {
                int t = wstart + i;
                float acc = cb[f];
                for (int k = 0; k < KK; ++k) {
                    int tt = t + k - 15;
                    float x = (tt >= 0 && tt < T) ? pa[(size_t)b * T + tt] : 0.f;
                    acc += x * ck[k * F + f];
                }
                fsh[i][f] = acc;
            } else if (i < WIN) {
                fsh[i][f] = 0.f;
            }
        }
        if (tid < D) {
            const float* pp = pq4 + (size_t)b * 4 * D;
            pqs[tid] = (pp[tid] + pp[D + tid]) + (pp[2 * D + tid] + pp[3 * D + tid]) + sb[tid];
        }
        __syncthreads();

        // finish energies: wave i sums the 8 w-partials (fixed order) then tanh
        if (wave < wlen) {
            int i = wave;
            const float2* vp = (const float2*)vpart + (size_t)b * 8 * (WIN * 64);
            float2 s2 = {0.f, 0.f};
            #pragma unroll
            for (int w = 0; w < 8; ++w) {
                float2 v = vp[(size_t)w * (WIN * 64) + i * 64 + lane];
                s2.x += v.x;
                s2.y += v.y;
            }
            ((float2*)vsh[i])[lane] = s2;           // save raw val[i][:]
            const float2* Wl2 = (const float2*)Wloc;
            float p0 = 0.f, p1 = 0.f;
            #pragma unroll
            for (int f = 0; f < F; ++f) {
                float fv = fsh[i][f];
                float2 wv = Wl2[f * 64 + lane];
                p0 += fv * wv.x; p1 += fv * wv.y;
            }
            int c0 = 2 * lane, c1 = c0 + 1;
            float x = sv[c0] * tanhf(s2.x + pqs[c0] + p0)
                    + sv[c1] * tanhf(s2.y + pqs[c1] + p1);
            for (int o = 32; o > 0; o >>= 1) x += __shfl_xor(x, o);
            if (lane == 0) esh[i] = x;
        }
        __syncthreads();

        if (tid == 0) {
            float a[WIN];
            int best = 0;
            float mx = esh[0];
            for (int i = 1; i < wlen; ++i) if (esh[i] > mx) mx = esh[i];
            float s = 0.f;
            for (int i = 0; i < wlen; ++i) { a[i] = expf(esh[i] - mx); s += a[i]; }
            float inv = 1.f / s;
            float ab = -1.f;
            for (int i = 0; i < wlen; ++i) {
                a[i] *= inv;
                if (a[i] > ab) { ab = a[i]; best = i; }
            }
            for (int i = 0; i < WIN; ++i) ash[i] = (i < wlen) ? a[i] : 0.f;
            sbest = wstart + best;
        }
        __syncthreads();

        // attention = sum_i a_i * val[i][:]
        if (tid < D) {
            float a = 0.f;
            for (int i = 0; i < wlen; ++i) a += ash[i] * vsh[i][tid];
            out[b * D + tid] = a;
        }
    } else {
        // ---------------- degenerate: reduce part (fixed order) + GEMV ----------
        float* ctxs = cg;
        float* gpart = cg + DM;
        float s = 0.f;
        #pragma unroll 8
        for (int cc = 0; cc < NCH; ++cc)
            s += part[((size_t)b * NCH + cc) * DM + tid];
        ctxs[tid] = s;
        __syncthreads();
        {
            int col = tid & 127, j = tid >> 7;
            const float* wp = Wm + (size_t)(j * 128) * D + col;
            float acc = 0.f;
            for (int mm = 0; mm < 128; ++mm)
                acc += ctxs[j * 128 + mm] * wp[(size_t)mm * D];
            gpart[j * D + col] = acc;
        }
        __syncthreads();
        if (tid < D)
            out[b * D + tid] = gpart[tid] + gpart[D + tid] + gpart[2 * D + tid] + gpart[3 * D + tid];
    }

    // ---------------- [B,T] outputs + argmax ----------------
    {
        float invT = 1.f / (float)T;
        for (int t = tid; t < T; t += 512) {
            float a;
            if (wlen == 0) a = invT;
            else a = (t >= wstart && t < wstart + wlen) ? ash[t - wstart] : 0.f;
            out[OUT_ALIGN + b * T + t] = a;
            out[OUT_NEXT + b * T + t] = pa[(size_t)b * T + t] + a;
        }
        if (tid == 0) out[OUT_ARG + b] = (float)((wlen > 0) ? sbest : 0);
    }
}

// ---------------- K2L: lowmem all-in-one fallback ----------
__global__ void __launch_bounds__(512)
K2L(const float* __restrict__ q, const float* __restrict__ mem,
    const float* __restrict__ pa, const int* __restrict__ pm, const int* __restrict__ ml,
    const float* __restrict__ Wq, const float* __restrict__ Wm,
    const float* __restrict__ ck, const float* __restrict__ cb,
    const float* __restrict__ Wloc, const float* __restrict__ sv,
    const float* __restrict__ sb, float* __restrict__ out) {
    __shared__ __align__(16) float mrow[WIN][DM];
    __shared__ float fsh[WIN][F];
    __shared__ float2 pacc2[WIN][8][64];
    __shared__ float vsh[WIN][D];
    __shared__ float pqs[D];
    __shared__ float esh[WIN];
    __shared__ float ash[WIN];
    __shared__ int   sbest;

    int b = blockIdx.x;
    int tid = threadIdx.x;
    int lane = tid & 63;
    int wave = tid >> 6;
    int p = pm[b], L = ml[b];
    int wstart = p, wlen = 0;
    if (p < L) { int we = p + WIN; if (we > L) we = L; wlen = we - p; }

    if (wlen > 0) {
        for (int e = tid; e < WIN * DM; e += 512) {
            int i = e >> 9, m = e & 511;
            mrow[i][m] = (i < wlen) ? mem[((size_t)b * T + wstart + i) * DM + m] : 0.f;
        }
        if (tid < WIN * F) {
            int i = tid >> 5, f = tid & 31;
            if (i < wlen) {
                int t = wstart + i;
                float acc = cb[f];
                for (int k = 0; k < KK; ++k) {
                    int tt = t + k - 15;
                    float x = (tt >= 0 && tt < T) ? pa[(size_t)b * T + tt] : 0.f;
                    acc += x * ck[k * F + f];
                }
                fsh[i][f] = acc;
            } else if (i < WIN) {
                fsh[i][f] = 0.f;
            }
        }
        {
            int d = tid & 127, j = tid >> 7;
            int k0 = j * 256;
            const float* qp = q + (size_t)b * DQ + k0;
            float acc = 0.f;
            for (int k = 0; k < 256; ++k)
                acc += qp[k] * Wq[(size_t)(k0 + k) * D + d];
            ((float*)pacc2)[j * D + d] = acc;
            __syncthreads();
            if (tid < D) {
                const float* pp = (const float*)pacc2;
                pqs[tid] = (pp[tid] + pp[D + tid]) + (pp[2 * D + tid] + pp[3 * D + tid]) + sb[tid];
            }
        }
        __syncthreads();
        {
            const float2* Wm2 = (const float2*)Wm;
            float2 acc[WIN];
            #pragma unroll
            for (int i = 0; i < WIN; ++i) { acc[i].x = 0.f; acc[i].y = 0.f; }
            int m0 = wave * 64;
            for (int mm = 0; mm < 64; ++mm) {
                int m = m0 + mm;
                float2 wrow = Wm2[(size_t)m * 64 + lane];
                #pragma unroll
                for (int i = 0; i < WIN; ++i) {
                    float a = mrow[i][m];
                    acc[i].x += a * wrow.x;
                    acc[i].y += a * wrow.y;
                }
            }
            #pragma unroll
            for (int i = 0; i < WIN; ++i) pacc2[i][wave][lane] = acc[i];
        }
        __syncthreads();
        if (wave < wlen) {
            int i = wave;
            float2 s2 = {0.f, 0.f};
            #pragma unroll
            for (int w = 0; w < 8; ++w) {
                s2.x += pacc2[i][w][lane].x;
                s2.y += pacc2[i][w][lane].y;
            }
            ((float2*)vsh[i])[lane] = s2;
            const float2* Wl2 = (const float2*)Wloc;
            float p0 = 0.f, p1 = 0.f;
            #pragma unroll
            for (int f = 0; f < F; ++f) {
                float fv = fsh[i][f];
                float2 wv = Wl2[f * 64 + lane];
                p0 += fv * wv.x; p1 += fv * wv.y;
            }
            int c0 = 2 * lane, c1 = c0 + 1;
            float x = sv[c0] * tanhf(s2.x + pqs[c0] + p0)
                    + sv[c1] * tanhf(s2.y + pqs[c1] + p1);
            for (int o = 32; o > 0; o >>= 1) x += __shfl_xor(x, o);
            if (lane == 0) esh[i] = x;
        }
        __syncthreads();
        if (tid == 0) {
            float a[WIN];
            int best = 0;
            float mx = esh[0];
            for (int i = 1; i < wlen; ++i) if (esh[i] > mx) mx = esh[i];
            float s = 0.f;
            for (int i = 0; i < wlen; ++i) { a[i] = expf(esh[i] - mx); s += a[i]; }
            float inv = 1.f / s;
            float ab = -1.f;
            for (int i = 0; i < wlen; ++i) {
                a[i] *= inv;
                if (a[i] > ab) { ab = a[i]; best = i; }
            }
            for (int i = 0; i < WIN; ++i) ash[i] = (i < wlen) ? a[i] : 0.f;
            sbest = wstart + best;
        }
        __syncthreads();
        if (tid < D) {
            float a = 0.f;
            for (int i = 0; i < wlen; ++i) a += ash[i] * vsh[i][tid];
            out[b * D + tid] = a;
        }
    } else {
        float* ctxs = (float*)mrow;
        float* gpart = ((float*)mrow) + DM;
        const float* mp = mem + (size_t)b * T * DM + tid;
        float a0 = 0.f, a1 = 0.f, a2 = 0.f, a3 = 0.f;
        int t = 0;
        for (; t + 4 <= T; t += 4) {
            a0 += mp[0]; a1 += mp[DM]; a2 += mp[2 * DM]; a3 += mp[3 * DM];
            mp += 4 * (size_t)DM;
        }
        for (; t < T; ++t) { a0 += *mp; mp += DM; }
        ctxs[tid] = ((a0 + a1) + (a2 + a3)) * (1.f / (float)T);
        __syncthreads();
        {
            int col = tid & 127, j = tid >> 7;
            const float* wp = Wm + (size_t)(j * 128) * D + col;
            float acc = 0.f;
            for (int mm = 0; mm < 128; ++mm)
                acc += ctxs[j * 128 + mm] * wp[(size_t)mm * D];
            gpart[j * D + col] = acc;
        }
        __syncthreads();
        if (tid < D)
            out[b * D + tid] = gpart[tid] + gpart[D + tid] + gpart[2 * D + tid] + gpart[3 * D + tid];
    }

    {
        float invT = 1.f / (float)T;
        for (int t = tid; t < T; t += 512) {
            float a;
            if (wlen == 0) a = invT;
            else a = (t >= wstart && t < wstart + wlen) ? ash[t - wstart] : 0.f;
            out[OUT_ALIGN + b * T + t] = a;
            out[OUT_NEXT + b * T + t] = pa[(size_t)b * T + t] + a;
        }
        if (tid == 0) out[OUT_ARG + b] = (float)((wlen > 0) ? sbest : 0);
    }
}

extern "C" void kernel_launch(void* const* d_in, const int* in_sizes, int n_in,
                              void* d_out, int out_size, void* d_ws, size_t ws_size,
                              hipStream_t stream) {
    const float* query = (const float*)d_in[0];
    const float* memory = (const float*)d_in[1];
    const float* prev_align = (const float*)d_in[2];
    const int* prev_max = (const int*)d_in[3];
    const int* mem_len = (const int*)d_in[4];
    const float* Wq = (const float*)d_in[5];
    const float* Wm = (const float*)d_in[6];
    const float* ck = (const float*)d_in[7];
    const float* cb = (const float*)d_in[8];
    const float* Wloc = (const float*)d_in[9];
    const float* sv = (const float*)d_in[10];
    const float* sb = (const float*)d_in[11];
    float* out = (float*)d_out;

    float* part = (float*)d_ws;
    float* pq4 = (float*)d_ws + PQ4_OFF;
    float* vpart = (float*)d_ws + VP_OFF;

    size_t need = (size_t)(VP_OFF + B * 8 * WIN * 64 * 2) * 4;
    int lowmem = (ws_size < need) ? 1 : 0;

    if (!lowmem) {
        K1<<<NCS + B + NPQ, 512, 0, stream>>>(query, memory, prev_max, mem_len,
                                              Wq, Wm, part, pq4, vpart);
        K2<<<B, 512, 0, stream>>>(prev_align, prev_max, mem_len, Wm, ck, cb,
                                  Wloc, sv, sb, part, pq4, vpart, out);
    } else {
        K2L<<<B, 512, 0, stream>>>(query, memory, prev_align, prev_max, mem_len,
                                   Wq, Wm, ck, cb, Wloc, sv, sb, out);
    }
}